// Round 4
// baseline (914.509 us; speedup 1.0000x reference)
//
#include <hip/hip_runtime.h>

#define EMBED 128
#define NCODE 10000
#define NSAMP 16384
#define NCODE_PAD 10240
#define NSPLIT 4
#define SPLIT_N 2560
#define CHUNKS_PER_SPLIT 20      // 20 chunks of 128 codes per split
#define OUT_ELEMS (NSAMP * EMBED)
#define TAU 0.005f               // rescue gap threshold (>=5x split-bf16 err bound)

typedef float f32x4 __attribute__((ext_vector_type(4)));
typedef short s16x8 __attribute__((ext_vector_type(8)));
typedef unsigned short ushort_t;

// ---- ws byte offsets (~11.5 MB) ----
#define OFF_CH  0               // 10240*128 bf16 hi  (2.62 MB)
#define OFF_CL  2621440         // bf16 lo
#define OFF_CT  5242880         // CT fp32 [n][k]     (5.24 MB)
#define OFF_CN  10485760        // cnorm fp32 [10240]
#define OFF_KEY 10526720        // candKey u64 [16384][4]
#define OFF_C2  11051008        // cand2 u32  [16384][4]
#define OFF_IDX 11313152        // idxf  i32  [16384]
#define OFF_RL  11378688        // rescue list
#define OFF_CNT 11444224        // rescue counter

__device__ __forceinline__ unsigned short f2bf(float f) {   // RNE fp32->bf16
    unsigned u = __float_as_uint(f);
    return (unsigned short)((u + 0x7fffu + ((u >> 16) & 1u)) >> 16);
}
__device__ __forceinline__ float bf2f(unsigned short h) {
    return __uint_as_float(((unsigned)h) << 16);
}
__device__ __forceinline__ unsigned ordf(float f) {         // order-preserving fp32->u32
    unsigned u = __float_as_uint(f);
    return (u & 0x80000000u) ? ~u : (u | 0x80000000u);
}
__device__ __forceinline__ float unordf(unsigned o) {
    return __uint_as_float((o & 0x80000000u) ? (o ^ 0x80000000u) : ~o);
}

// ---- prep: cnorm (exact fp32) + zero loss/counter ----
__global__ __launch_bounds__(256) void prep_norm(const float* __restrict__ C,
                                                 float* __restrict__ cnorm,
                                                 float* __restrict__ out,
                                                 int* __restrict__ counter) {
    int j = blockIdx.x * 256 + threadIdx.x;
    if (j == 0) { out[OUT_ELEMS] = 0.f; *counter = 0; }
    if (j >= NCODE_PAD) return;
    if (j >= NCODE) { cnorm[j] = 3.0e38f; return; }
    float s = 0.f;
#pragma unroll 8
    for (int d = 0; d < EMBED; ++d) {
        float v = C[d * NCODE + j];
        s = fmaf(v, v, s);
    }
    cnorm[j] = s;
}

// ---- prep: C -> Ch/Cl pre-swizzled [chunk][ks][quad][nl128][j8] + CT fp32 [n][k] ----
__global__ __launch_bounds__(256) void prep_c(const float* __restrict__ C,
                                              ushort_t* __restrict__ Ch,
                                              ushort_t* __restrict__ Cl,
                                              float* __restrict__ CT) {
    int o = blockIdx.x * 256 + threadIdx.x;      // 163840 threads
    int e0 = o * 8;
    int chunk  = e0 >> 12;                        // chunk*4+ks
    int within = e0 & 4095;
    int q  = within >> 10;
    int nl = (within >> 3) & 127;
    int n  = (chunk >> 2) * 128 + nl;
    int k0 = (chunk & 3) * 32 + q * 8;
    s16x8 vh, vl;
    float ct[8];
#pragma unroll
    for (int j = 0; j < 8; ++j) {
        int k = k0 + j;
        float f = (n < NCODE) ? C[(size_t)k * NCODE + n] : 0.f;
        unsigned short h = f2bf(f);
        vh[j] = (short)h;
        vl[j] = (short)f2bf(f - bf2f(h));
        ct[j] = f;
    }
    *(s16x8*)(Ch + e0) = vh;
    *(s16x8*)(Cl + e0) = vl;
    *(float4*)(CT + (size_t)n * EMBED + k0)     = make_float4(ct[0], ct[1], ct[2], ct[3]);
    *(float4*)(CT + (size_t)n * EMBED + k0 + 4) = make_float4(ct[4], ct[5], ct[6], ct[7]);
}

// ---- main: persistent-A split-bf16 MFMA + running top-2 over 20 n-chunks ----
// grid (128, 4): Bm = m-group of 128 rows, split = n-range of 2560 codes.
// 4 waves; wave owns 32 m-rows (2 m-blocks of 16), all 128 n of each chunk.
__global__ __launch_bounds__(256, 2) void vq2(const float* __restrict__ X,
                                              const ushort_t* __restrict__ Ch,
                                              const ushort_t* __restrict__ Cl,
                                              const float* __restrict__ cnorm,
                                              unsigned long long* __restrict__ candKey,
                                              unsigned* __restrict__ cand2) {
    __shared__ ushort_t Bs[2 * 16384];   // Bh (32 KB) | Bl (32 KB), [ks][quad][nl][j8]
    const int t    = threadIdx.x;
    const int lane = t & 63;
    const int wave = t >> 6;
    const int l15  = lane & 15;
    const int quad = lane >> 4;
    const int m0   = blockIdx.x * 128 + wave * 32;
    const int split = blockIdx.y;

    // ---- A-frags persistent in registers: load X fp32, RNE-split to bf16 h/l ----
    s16x8 ah[2][4], al[2][4];
#pragma unroll
    for (int mb = 0; mb < 2; ++mb)
#pragma unroll
        for (int ks = 0; ks < 4; ++ks) {
            const float* src = X + (size_t)(m0 + mb * 16 + l15) * EMBED + ks * 32 + quad * 8;
            float4 f0 = *(const float4*)src;
            float4 f1 = *(const float4*)(src + 4);
            float f[8] = {f0.x, f0.y, f0.z, f0.w, f1.x, f1.y, f1.z, f1.w};
            s16x8 vh, vl;
#pragma unroll
            for (int j = 0; j < 8; ++j) {
                unsigned short h = f2bf(f[j]);
                vh[j] = (short)h;
                vl[j] = (short)f2bf(f[j] - bf2f(h));
            }
            ah[mb][ks] = vh;
            al[mb][ks] = vl;
        }

    // per-thread running top-2 for 8 rows (row q8=mb*4+r -> m = m0+mb*16+quad*4+r)
    float v1[8], v2r[8];
    int   j1[8];
#pragma unroll
    for (int i = 0; i < 8; ++i) { v1[i] = 3.4e38f; v2r[i] = 3.4e38f; j1[i] = 0; }

    auto ldsw = (__attribute__((address_space(3))) ushort_t*)Bs;

    for (int c = 0; c < CHUNKS_PER_SPLIT; ++c) {
        const int chunk = split * CHUNKS_PER_SPLIT + c;
        const int nbase = chunk * 128;
        __syncthreads();
        // ---- stage B chunk (h+l, 64 KB): wave w copies its 8 KB of each half ----
        {
            const ushort_t* sH = Ch + (size_t)chunk * 16384 + wave * 4096 + lane * 8;
            const ushort_t* sL = Cl + (size_t)chunk * 16384 + wave * 4096 + lane * 8;
#pragma unroll
            for (int i = 0; i < 8; ++i) {
                __builtin_amdgcn_global_load_lds(
                    (const __attribute__((address_space(1))) void*)(sH + i * 512),
                    (__attribute__((address_space(3))) void*)(ldsw + wave * 4096 + i * 512),
                    16, 0, 0);
                __builtin_amdgcn_global_load_lds(
                    (const __attribute__((address_space(1))) void*)(sL + i * 512),
                    (__attribute__((address_space(3))) void*)(ldsw + 16384 + wave * 4096 + i * 512),
                    16, 0, 0);
            }
        }
        __syncthreads();

        f32x4 acc[2][8];
#pragma unroll
        for (int mb = 0; mb < 2; ++mb)
#pragma unroll
            for (int nb = 0; nb < 8; ++nb) acc[mb][nb] = (f32x4){0.f, 0.f, 0.f, 0.f};

#pragma unroll
        for (int ks = 0; ks < 4; ++ks) {
            const int fb = ks * 4096 + quad * 1024 + l15 * 8;
            {   // Bh: used by both Ah and Al products
                s16x8 bh[8];
#pragma unroll
                for (int nb = 0; nb < 8; ++nb)
                    bh[nb] = *(const s16x8*)&Bs[fb + nb * 128];
#pragma unroll
                for (int mb = 0; mb < 2; ++mb)
#pragma unroll
                    for (int nb = 0; nb < 8; ++nb) {
                        acc[mb][nb] = __builtin_amdgcn_mfma_f32_16x16x32_bf16(ah[mb][ks], bh[nb], acc[mb][nb], 0, 0, 0);
                        acc[mb][nb] = __builtin_amdgcn_mfma_f32_16x16x32_bf16(al[mb][ks], bh[nb], acc[mb][nb], 0, 0, 0);
                    }
            }
            {   // Bl: only Ah product
                s16x8 bl[8];
#pragma unroll
                for (int nb = 0; nb < 8; ++nb)
                    bl[nb] = *(const s16x8*)&Bs[16384 + fb + nb * 128];
#pragma unroll
                for (int mb = 0; mb < 2; ++mb)
#pragma unroll
                    for (int nb = 0; nb < 8; ++nb)
                        acc[mb][nb] = __builtin_amdgcn_mfma_f32_16x16x32_bf16(ah[mb][ks], bl[nb], acc[mb][nb], 0, 0, 0);
            }
        }

        // ---- running top-2 update (dist = ||c||^2 - 2 s.c, argmin-equivalent) ----
        float cn[8];
#pragma unroll
        for (int nb = 0; nb < 8; ++nb) cn[nb] = cnorm[nbase + nb * 16 + l15];
#pragma unroll
        for (int mb = 0; mb < 2; ++mb)
#pragma unroll
            for (int r = 0; r < 4; ++r) {
                const int q8 = mb * 4 + r;
#pragma unroll
                for (int nb = 0; nb < 8; ++nb) {
                    float d = fmaf(-2.f, acc[mb][nb][r], cn[nb]);
                    int j = nbase + nb * 16 + l15;
                    if (d < v1[q8])       { v2r[q8] = v1[q8]; v1[q8] = d; j1[q8] = j; }
                    else if (d < v2r[q8]) { v2r[q8] = d; }
                }
            }
    }

    // ---- reduce top-2 across the 16 n-lanes (xor 1,2,4,8 stays within quad) ----
#pragma unroll
    for (int off = 1; off < 16; off <<= 1)
#pragma unroll
        for (int q8 = 0; q8 < 8; ++q8) {
            float ov1 = __shfl_xor(v1[q8], off, 64);
            int   oj1 = __shfl_xor(j1[q8], off, 64);
            float ov2 = __shfl_xor(v2r[q8], off, 64);
            float hi = fmaxf(v1[q8], ov1);
            v2r[q8] = fminf(fminf(v2r[q8], ov2), hi);
            if (ov1 < v1[q8] || (ov1 == v1[q8] && oj1 < j1[q8])) { v1[q8] = ov1; j1[q8] = oj1; }
        }
    if (l15 == 0) {
#pragma unroll
        for (int mb = 0; mb < 2; ++mb)
#pragma unroll
            for (int r = 0; r < 4; ++r) {
                int m = m0 + mb * 16 + quad * 4 + r;
                int q8 = mb * 4 + r;
                candKey[(size_t)m * NSPLIT + split] =
                    ((unsigned long long)ordf(v1[q8]) << 32) | (unsigned)j1[q8];
                cand2[(size_t)m * NSPLIT + split] = ordf(v2r[q8]);
            }
    }
}

// ---- fused finalize + output: merge 4 candidates, flag near-ties, gather, loss ----
__global__ __launch_bounds__(256) void outfin_k(const float* __restrict__ X,
                                                const float* __restrict__ CT,
                                                const unsigned long long* __restrict__ candKey,
                                                const unsigned* __restrict__ cand2,
                                                int* __restrict__ idxf,
                                                int* __restrict__ rlist,
                                                int* __restrict__ counter,
                                                float* __restrict__ out) {
    __shared__ float red[4];
    const int t = threadIdx.x;
    const int m = blockIdx.x * 8 + (t >> 5);
    const int l = t & 31;

    int code = 0;
    if (l == 0) {
        unsigned long long best = 0xffffffffffffffffull;
        float v2 = 3.4e38f;
#pragma unroll
        for (int s = 0; s < NSPLIT; ++s) {
            unsigned long long k = candKey[(size_t)m * NSPLIT + s];
            unsigned o2 = cand2[(size_t)m * NSPLIT + s];
            if (k < best) {
                if (best != 0xffffffffffffffffull)
                    v2 = fminf(v2, unordf((unsigned)(best >> 32)));
                best = k;
                v2 = fminf(v2, unordf(o2));
            } else {
                v2 = fminf(v2, unordf((unsigned)(k >> 32)));
            }
        }
        code = (int)(unsigned)(best & 0xffffffffu);
        idxf[m] = code;
        float v1 = unordf((unsigned)(best >> 32));
        if (v2 - v1 <= TAU) rlist[atomicAdd(counter, 1)] = m;
    }
    code = __shfl(code, 0, 32);

    float4 q = *(const float4*)(CT + (size_t)code * EMBED + l * 4);
    float4 x = *(const float4*)(X + (size_t)m * EMBED + l * 4);
    *(float4*)(out + (size_t)m * EMBED + l * 4) = q;
    float dx = q.x - x.x, dy = q.y - x.y, dz = q.z - x.z, dw = q.w - x.w;
    float lsum = dx * dx + dy * dy + dz * dz + dw * dw;
#pragma unroll
    for (int off = 1; off < 64; off <<= 1) lsum += __shfl_xor(lsum, off, 64);
    if ((t & 63) == 0) red[t >> 6] = lsum;
    __syncthreads();
    if (t == 0)
        atomicAdd(out + OUT_ELEMS,
                  (red[0] + red[1] + red[2] + red[3]) * (1.25f / (float)OUT_ELEMS));
}

// ---- rescue: exact fp32 argmin for flagged samples, one sample per wave ----
__global__ __launch_bounds__(256) void rescue_k(const float* __restrict__ X,
                                                const float* __restrict__ CT,
                                                const float* __restrict__ cnorm,
                                                const int* __restrict__ rlist,
                                                const int* __restrict__ counter,
                                                const int* __restrict__ idxf,
                                                float* __restrict__ out) {
    __shared__ float xs[4][EMBED];
    const int t = threadIdx.x;
    const int lane = t & 63;
    const int wave = t >> 6;
    const int wslot = blockIdx.x * 4 + wave;        // 512 wave slots
    const int cnt = *counter;
    const int iters = (cnt + 511) / 512;            // block-uniform loop count

    for (int it = 0; it < iters; ++it) {
        int s = it * 512 + wslot;
        bool active = (s < cnt);
        int m = active ? rlist[s] : 0;
        __syncthreads();
        if (active && lane < 32) {
            float4 v = *(const float4*)(X + (size_t)m * EMBED + lane * 4);
            xs[wave][lane * 4 + 0] = v.x; xs[wave][lane * 4 + 1] = v.y;
            xs[wave][lane * 4 + 2] = v.z; xs[wave][lane * 4 + 3] = v.w;
        }
        __syncthreads();
        if (!active) continue;

        unsigned long long bk = 0xffffffffffffffffull;
        for (int j = lane; j < NCODE; j += 64) {
            const float* cr = CT + (size_t)j * EMBED;
            float dot = 0.f;
#pragma unroll 8
            for (int k = 0; k < EMBED; k += 4) {
                float4 cv = *(const float4*)(cr + k);
                dot = fmaf(xs[wave][k + 0], cv.x, dot);
                dot = fmaf(xs[wave][k + 1], cv.y, dot);
                dot = fmaf(xs[wave][k + 2], cv.z, dot);
                dot = fmaf(xs[wave][k + 3], cv.w, dot);
            }
            float d = fmaf(-2.f, dot, cnorm[j]);
            unsigned long long key = ((unsigned long long)ordf(d) << 32) | (unsigned)j;
            if (key < bk) bk = key;
        }
#pragma unroll
        for (int off = 1; off < 64; off <<= 1) {
            unsigned long long o = __shfl_xor(bk, off, 64);
            if (o < bk) bk = o;
        }
        int jn = (int)(unsigned)(bk & 0xffffffffu);
        int jo = idxf[m];
        if (jn != jo) {
            float delta = 0.f;
            if (lane < 32) {
                float4 qn = *(const float4*)(CT + (size_t)jn * EMBED + lane * 4);
                float4 qo = *(const float4*)(CT + (size_t)jo * EMBED + lane * 4);
                float x0 = xs[wave][lane * 4 + 0], x1 = xs[wave][lane * 4 + 1];
                float x2 = xs[wave][lane * 4 + 2], x3 = xs[wave][lane * 4 + 3];
                *(float4*)(out + (size_t)m * EMBED + lane * 4) = qn;
                float dn = (qn.x - x0) * (qn.x - x0) + (qn.y - x1) * (qn.y - x1)
                         + (qn.z - x2) * (qn.z - x2) + (qn.w - x3) * (qn.w - x3);
                float dp = (qo.x - x0) * (qo.x - x0) + (qo.y - x1) * (qo.y - x1)
                         + (qo.z - x2) * (qo.z - x2) + (qo.w - x3) * (qo.w - x3);
                delta = dn - dp;
            }
#pragma unroll
            for (int off = 1; off < 32; off <<= 1) delta += __shfl_xor(delta, off, 32);
            if (lane == 0)
                atomicAdd(out + OUT_ELEMS, delta * (1.25f / (float)OUT_ELEMS));
        }
    }
}

extern "C" void kernel_launch(void* const* d_in, const int* in_sizes, int n_in,
                              void* d_out, int out_size, void* d_ws, size_t ws_size,
                              hipStream_t stream) {
    const float* X = (const float*)d_in[0];   // (16384,128) fp32
    const float* C = (const float*)d_in[1];   // (128,10000) fp32
    float* out = (float*)d_out;
    char* ws = (char*)d_ws;

    ushort_t* Ch = (ushort_t*)(ws + OFF_CH);
    ushort_t* Cl = (ushort_t*)(ws + OFF_CL);
    float* CT    = (float*)(ws + OFF_CT);
    float* cnorm = (float*)(ws + OFF_CN);
    unsigned long long* candKey = (unsigned long long*)(ws + OFF_KEY);
    unsigned* cand2 = (unsigned*)(ws + OFF_C2);
    int* idxf    = (int*)(ws + OFF_IDX);
    int* rlist   = (int*)(ws + OFF_RL);
    int* counter = (int*)(ws + OFF_CNT);

    prep_norm<<<NCODE_PAD / 256, 256, 0, stream>>>(C, cnorm, out, counter);
    prep_c<<<(NCODE_PAD * 16) / 256, 256, 0, stream>>>(C, Ch, Cl, CT);
    vq2<<<dim3(NSAMP / 128, NSPLIT), 256, 0, stream>>>(X, Ch, Cl, cnorm, candKey, cand2);
    outfin_k<<<NSAMP / 8, 256, 0, stream>>>(X, CT, candKey, cand2, idxf, rlist, counter, out);
    rescue_k<<<128, 256, 0, stream>>>(X, CT, cnorm, rlist, counter, idxf, out);
}

// Round 5
// 411.023 us; speedup vs baseline: 2.2250x; 2.2250x over previous
//
#include <hip/hip_runtime.h>

#define EMBED 128
#define NCODE 10000
#define NSAMP 16384
#define NCODE_PAD 10240
#define NSPLIT 8
#define SPLIT_CODES 1280
#define NCHUNK 20                 // chunks per split, 64 codes each
#define CHUNK_ELEMS 9216          // ushorts per chunk per (h|l): 2mb*18kg*256
#define OUT_ELEMS (NSAMP * EMBED)
#define TAU 0.008f                // rescue gap threshold (> split-bf16 err bound)

typedef float f32x16 __attribute__((ext_vector_type(16)));
typedef short s16x8 __attribute__((ext_vector_type(8)));
typedef unsigned short ushort_t;

// ---- ws byte offsets (~12.9 MB) ----
#define OFF_AH  0                 // Ah: 10240*144 bf16 swizzled (2.95 MB)
#define OFF_AL  2949120
#define OFF_CT  5898240           // CT fp32 [n][k] (5.24 MB)
#define OFF_CN  11141120          // cnorm fp32 [10240]
#define OFF_KEY 11182080          // candKey u64 [16384][8]
#define OFF_C2  12230656          // cand2 u32 [16384][8]
#define OFF_IDX 12754944
#define OFF_RL  12820480
#define OFF_CNT 12886016

__device__ __forceinline__ unsigned short f2bf(float f) {   // RNE fp32->bf16
    unsigned u = __float_as_uint(f);
    return (unsigned short)((u + 0x7fffu + ((u >> 16) & 1u)) >> 16);
}
__device__ __forceinline__ float bf2f(unsigned short h) {
    return __uint_as_float(((unsigned)h) << 16);
}
__device__ __forceinline__ unsigned ordf(float f) {         // order-preserving fp32->u32
    unsigned u = __float_as_uint(f);
    return (u & 0x80000000u) ? ~u : (u | 0x80000000u);
}
__device__ __forceinline__ float unordf(unsigned o) {
    return __uint_as_float((o & 0x80000000u) ? (o ^ 0x80000000u) : ~o);
}

// ---- prep: cnorm (exact fp32) + zero loss/counter ----
__global__ __launch_bounds__(256) void prep_norm(const float* __restrict__ C,
                                                 float* __restrict__ cnorm,
                                                 float* __restrict__ out,
                                                 int* __restrict__ counter) {
    int j = blockIdx.x * 256 + threadIdx.x;
    if (j == 0) { out[OUT_ELEMS] = 0.f; *counter = 0; }
    if (j >= NCODE_PAD) return;
    if (j >= NCODE) { cnorm[j] = 3.0e38f; return; }
    float s = 0.f;
#pragma unroll 8
    for (int d = 0; d < EMBED; ++d) {
        float v = C[d * NCODE + j];
        s = fmaf(v, v, s);
    }
    cnorm[j] = s;
}

// ---- prep: codes -> A-stream (swizzled, K'=144 with cn in slot 128) + CT ----
// layout: [split][chunk][mb][kg(=ks*2+kh)][row32][8]
__global__ __launch_bounds__(256) void prep_c2(const float* __restrict__ C,
                                               const float* __restrict__ cnorm,
                                               ushort_t* __restrict__ Ah,
                                               ushort_t* __restrict__ Al,
                                               float* __restrict__ CT) {
    int o = blockIdx.x * 256 + threadIdx.x;   // 184320 threads
    int n  = o % NCODE_PAD;
    int kg = o / NCODE_PAD;                   // 0..17
    int split = n / SPLIT_CODES;
    int rem   = n % SPLIT_CODES;
    int chunk = rem >> 6;
    int mb    = (rem >> 5) & 1;
    int row   = rem & 31;
    size_t eoff = ((size_t)((split * NCHUNK + chunk) * 2 + mb) * 18 + kg) * 256 + row * 8;

    float f[8];
    if (kg < 16) {
        int k0 = kg * 8;
#pragma unroll
        for (int j = 0; j < 8; ++j)
            f[j] = (n < NCODE) ? C[(size_t)(k0 + j) * NCODE + n] : 0.f;
        *(float4*)(CT + (size_t)n * EMBED + k0)     = make_float4(f[0], f[1], f[2], f[3]);
        *(float4*)(CT + (size_t)n * EMBED + k0 + 4) = make_float4(f[4], f[5], f[6], f[7]);
    } else if (kg == 16) {
        f[0] = cnorm[n];
#pragma unroll
        for (int j = 1; j < 8; ++j) f[j] = 0.f;
    } else {
#pragma unroll
        for (int j = 0; j < 8; ++j) f[j] = 0.f;
    }
    s16x8 vh, vl;
#pragma unroll
    for (int j = 0; j < 8; ++j) {
        unsigned short h = f2bf(f[j]);
        vh[j] = (short)h;
        vl[j] = (short)f2bf(f[j] - bf2f(h));
    }
    *(s16x8*)(Ah + eoff) = vh;
    *(s16x8*)(Al + eoff) = vl;
}

// ---- main: persistent-X (B-operand), streamed codes (A), 32x32x16 MFMA ----
// dist = [c,||c||^2] . [-2x, 1]  (3 split-bf16 products). Argmin is per-lane.
// grid (64, 8): block = 256 samples x 1280 codes. Wave owns 64 samples.
__global__ __launch_bounds__(256, 2) void vq3(const float* __restrict__ X,
                                              const ushort_t* __restrict__ Ah,
                                              const ushort_t* __restrict__ Al,
                                              unsigned long long* __restrict__ candKey,
                                              unsigned* __restrict__ cand2) {
    __shared__ ushort_t Bs[2 * CHUNK_ELEMS];   // 36 KB: [h 9216 | l 9216]
    const int t    = threadIdx.x;
    const int lane = t & 63;
    const int wave = t >> 6;
    const int ln   = lane & 31;
    const int kh   = lane >> 5;
    const int split = blockIdx.y;
    const int m0    = blockIdx.x * 256;

    // ---- persistent B frags: samples, split(-2x) + the "1" slot at k'=128 ----
    s16x8 bh[2][9], bl[2][9];
#pragma unroll
    for (int g = 0; g < 2; ++g) {
        int m = m0 + wave * 64 + g * 32 + ln;
#pragma unroll
        for (int ks = 0; ks < 8; ++ks) {
            const float* src = X + (size_t)m * EMBED + ks * 16 + kh * 8;
            float4 f0 = *(const float4*)src;
            float4 f1 = *(const float4*)(src + 4);
            float f[8] = {f0.x, f0.y, f0.z, f0.w, f1.x, f1.y, f1.z, f1.w};
            s16x8 vh, vl;
#pragma unroll
            for (int j = 0; j < 8; ++j) {
                float v = -2.f * f[j];
                unsigned short h = f2bf(v);
                vh[j] = (short)h;
                vl[j] = (short)f2bf(v - bf2f(h));
            }
            bh[g][ks] = vh;
            bl[g][ks] = vl;
        }
        s16x8 z = {0, 0, 0, 0, 0, 0, 0, 0};
        s16x8 one = z;
        if (kh == 0) one[0] = (short)0x3F80;   // bf16 1.0 at k'=128
        bh[g][8] = one;
        bl[g][8] = z;
    }

    float v1[2] = {3.4e38f, 3.4e38f}, v2[2] = {3.4e38f, 3.4e38f};
    int   j1[2] = {0, 0};

    auto ldsw = (__attribute__((address_space(3))) ushort_t*)Bs;
    const ushort_t* srcA = (wave < 2) ? Ah : Al;
    const int dstbase = (wave >> 1) * CHUNK_ELEMS + (wave & 1) * 4608;

    for (int c = 0; c < NCHUNK; ++c) {
        __syncthreads();
        // stage chunk (64 codes, h+l = 36 KB): each wave copies 9 KB
        const ushort_t* s = srcA + (size_t)(split * NCHUNK + c) * CHUNK_ELEMS
                            + (wave & 1) * 4608 + lane * 8;
#pragma unroll
        for (int i = 0; i < 9; ++i)
            __builtin_amdgcn_global_load_lds(
                (const __attribute__((address_space(1))) void*)(s + i * 512),
                (__attribute__((address_space(3))) void*)(ldsw + dstbase + i * 512),
                16, 0, 0);
        __syncthreads();

        const int cbase = split * SPLIT_CODES + c * 64 + 4 * kh;
#pragma unroll
        for (int mb = 0; mb < 2; ++mb) {
            f32x16 acc0 = {0,0,0,0,0,0,0,0,0,0,0,0,0,0,0,0};
            f32x16 acc1 = {0,0,0,0,0,0,0,0,0,0,0,0,0,0,0,0};
#pragma unroll
            for (int ks = 0; ks < 9; ++ks) {
                const int fo = (mb * 18 + ks * 2 + kh) * 256 + ln * 8;
                s16x8 a_h = *(const s16x8*)&Bs[fo];
                s16x8 a_l = *(const s16x8*)&Bs[CHUNK_ELEMS + fo];
                acc0 = __builtin_amdgcn_mfma_f32_32x32x16_bf16(a_h, bh[0][ks], acc0, 0, 0, 0);
                acc1 = __builtin_amdgcn_mfma_f32_32x32x16_bf16(a_h, bh[1][ks], acc1, 0, 0, 0);
                acc0 = __builtin_amdgcn_mfma_f32_32x32x16_bf16(a_h, bl[0][ks], acc0, 0, 0, 0);
                acc1 = __builtin_amdgcn_mfma_f32_32x32x16_bf16(a_h, bl[1][ks], acc1, 0, 0, 0);
                acc0 = __builtin_amdgcn_mfma_f32_32x32x16_bf16(a_l, bh[0][ks], acc0, 0, 0, 0);
                acc1 = __builtin_amdgcn_mfma_f32_32x32x16_bf16(a_l, bh[1][ks], acc1, 0, 0, 0);
            }
            // per-lane top-2 over the 16 code-rows this lane holds (no shuffles)
#pragma unroll
            for (int r = 0; r < 16; ++r) {
                int code = cbase + mb * 32 + ((r & 3) + 8 * (r >> 2));
                float d0 = acc0[r];
                if (d0 < v1[0]) { v2[0] = v1[0]; v1[0] = d0; j1[0] = code; }
                else            { v2[0] = fminf(v2[0], d0); }
                float d1 = acc1[r];
                if (d1 < v1[1]) { v2[1] = v1[1]; v1[1] = d1; j1[1] = code; }
                else            { v2[1] = fminf(v2[1], d1); }
            }
        }
    }

    // merge lane^32 (same sample, other code-half), emit per-split top-2
#pragma unroll
    for (int g = 0; g < 2; ++g) {
        float ov1 = __shfl_xor(v1[g], 32, 64);
        int   oj1 = __shfl_xor(j1[g], 32, 64);
        float ov2 = __shfl_xor(v2[g], 32, 64);
        float hi = fmaxf(v1[g], ov1);
        v2[g] = fminf(fminf(v2[g], ov2), hi);
        if (ov1 < v1[g] || (ov1 == v1[g] && oj1 < j1[g])) { v1[g] = ov1; j1[g] = oj1; }
        if (kh == 0) {
            int m = m0 + wave * 64 + g * 32 + ln;
            candKey[(size_t)m * NSPLIT + split] =
                ((unsigned long long)ordf(v1[g]) << 32) | (unsigned)j1[g];
            cand2[(size_t)m * NSPLIT + split] = ordf(v2[g]);
        }
    }
}

// ---- fused finalize + output: merge 8 candidates, flag near-ties, gather, loss ----
__global__ __launch_bounds__(256) void outfin_k(const float* __restrict__ X,
                                                const float* __restrict__ CT,
                                                const unsigned long long* __restrict__ candKey,
                                                const unsigned* __restrict__ cand2,
                                                int* __restrict__ idxf,
                                                int* __restrict__ rlist,
                                                int* __restrict__ counter,
                                                float* __restrict__ out) {
    __shared__ float red[4];
    const int t = threadIdx.x;
    const int m = blockIdx.x * 8 + (t >> 5);
    const int l = t & 31;

    int code = 0;
    if (l == 0) {
        unsigned long long best = 0xffffffffffffffffull;
        float v2 = 3.4e38f;
#pragma unroll
        for (int s = 0; s < NSPLIT; ++s) {
            unsigned long long k = candKey[(size_t)m * NSPLIT + s];
            unsigned o2 = cand2[(size_t)m * NSPLIT + s];
            if (k < best) {
                if (best != 0xffffffffffffffffull)
                    v2 = fminf(v2, unordf((unsigned)(best >> 32)));
                best = k;
                v2 = fminf(v2, unordf(o2));
            } else {
                v2 = fminf(v2, unordf((unsigned)(k >> 32)));
            }
        }
        code = (int)(unsigned)(best & 0xffffffffu);
        idxf[m] = code;
        float v1 = unordf((unsigned)(best >> 32));
        if (v2 - v1 <= TAU) rlist[atomicAdd(counter, 1)] = m;
    }
    code = __shfl(code, 0, 32);

    float4 q = *(const float4*)(CT + (size_t)code * EMBED + l * 4);
    float4 x = *(const float4*)(X + (size_t)m * EMBED + l * 4);
    *(float4*)(out + (size_t)m * EMBED + l * 4) = q;
    float dx = q.x - x.x, dy = q.y - x.y, dz = q.z - x.z, dw = q.w - x.w;
    float lsum = dx * dx + dy * dy + dz * dz + dw * dw;
#pragma unroll
    for (int off = 1; off < 64; off <<= 1) lsum += __shfl_xor(lsum, off, 64);
    if ((t & 63) == 0) red[t >> 6] = lsum;
    __syncthreads();
    if (t == 0)
        atomicAdd(out + OUT_ELEMS,
                  (red[0] + red[1] + red[2] + red[3]) * (1.25f / (float)OUT_ELEMS));
}

// ---- rescue: exact fp32 argmin, ONE SAMPLE PER BLOCK, 8-way ILP dot ----
__global__ __launch_bounds__(256) void rescue2(const float* __restrict__ X,
                                               const float* __restrict__ CT,
                                               const float* __restrict__ cnorm,
                                               const int* __restrict__ rlist,
                                               const int* __restrict__ counter,
                                               const int* __restrict__ idxf,
                                               float* __restrict__ out) {
    __shared__ float xs[EMBED];
    __shared__ unsigned long long wk[4];
    __shared__ int sjn;
    const int t = threadIdx.x;
    const int lane = t & 63;
    const int wave = t >> 6;
    const int cnt = *counter;

    for (int s = blockIdx.x; s < cnt; s += gridDim.x) {
        const int m = rlist[s];
        __syncthreads();   // protect xs/wk reuse across iterations
        if (t < 32) {
            float4 v = *(const float4*)(X + (size_t)m * EMBED + t * 4);
            xs[t * 4 + 0] = v.x; xs[t * 4 + 1] = v.y;
            xs[t * 4 + 2] = v.z; xs[t * 4 + 3] = v.w;
        }
        __syncthreads();

        unsigned long long bk = 0xffffffffffffffffull;
        for (int j = t; j < NCODE; j += 256) {
            const float* cr = CT + (size_t)j * EMBED;
            float a0 = 0.f, a1 = 0.f, a2 = 0.f, a3 = 0.f;
            float a4 = 0.f, a5 = 0.f, a6 = 0.f, a7 = 0.f;
#pragma unroll
            for (int kb = 0; kb < EMBED; kb += 32) {
                float4 c0 = *(const float4*)(cr + kb);
                float4 c1 = *(const float4*)(cr + kb + 4);
                float4 c2 = *(const float4*)(cr + kb + 8);
                float4 c3 = *(const float4*)(cr + kb + 12);
                float4 c4 = *(const float4*)(cr + kb + 16);
                float4 c5 = *(const float4*)(cr + kb + 20);
                float4 c6 = *(const float4*)(cr + kb + 24);
                float4 c7 = *(const float4*)(cr + kb + 28);
                a0 = fmaf(xs[kb + 0], c0.x, a0);  a0 = fmaf(xs[kb + 1], c0.y, a0);
                a0 = fmaf(xs[kb + 2], c0.z, a0);  a0 = fmaf(xs[kb + 3], c0.w, a0);
                a1 = fmaf(xs[kb + 4], c1.x, a1);  a1 = fmaf(xs[kb + 5], c1.y, a1);
                a1 = fmaf(xs[kb + 6], c1.z, a1);  a1 = fmaf(xs[kb + 7], c1.w, a1);
                a2 = fmaf(xs[kb + 8], c2.x, a2);  a2 = fmaf(xs[kb + 9], c2.y, a2);
                a2 = fmaf(xs[kb + 10], c2.z, a2); a2 = fmaf(xs[kb + 11], c2.w, a2);
                a3 = fmaf(xs[kb + 12], c3.x, a3); a3 = fmaf(xs[kb + 13], c3.y, a3);
                a3 = fmaf(xs[kb + 14], c3.z, a3); a3 = fmaf(xs[kb + 15], c3.w, a3);
                a4 = fmaf(xs[kb + 16], c4.x, a4); a4 = fmaf(xs[kb + 17], c4.y, a4);
                a4 = fmaf(xs[kb + 18], c4.z, a4); a4 = fmaf(xs[kb + 19], c4.w, a4);
                a5 = fmaf(xs[kb + 20], c5.x, a5); a5 = fmaf(xs[kb + 21], c5.y, a5);
                a5 = fmaf(xs[kb + 22], c5.z, a5); a5 = fmaf(xs[kb + 23], c5.w, a5);
                a6 = fmaf(xs[kb + 24], c6.x, a6); a6 = fmaf(xs[kb + 25], c6.y, a6);
                a6 = fmaf(xs[kb + 26], c6.z, a6); a6 = fmaf(xs[kb + 27], c6.w, a6);
                a7 = fmaf(xs[kb + 28], c7.x, a7); a7 = fmaf(xs[kb + 29], c7.y, a7);
                a7 = fmaf(xs[kb + 30], c7.z, a7); a7 = fmaf(xs[kb + 31], c7.w, a7);
            }
            float dot = ((a0 + a1) + (a2 + a3)) + ((a4 + a5) + (a6 + a7));
            float d = fmaf(-2.f, dot, cnorm[j]);
            unsigned long long key = ((unsigned long long)ordf(d) << 32) | (unsigned)j;
            if (key < bk) bk = key;
        }
#pragma unroll
        for (int off = 1; off < 64; off <<= 1) {
            unsigned long long o = __shfl_xor(bk, off, 64);
            if (o < bk) bk = o;
        }
        if (lane == 0) wk[wave] = bk;
        __syncthreads();
        if (t == 0) {
            unsigned long long b = wk[0];
            if (wk[1] < b) b = wk[1];
            if (wk[2] < b) b = wk[2];
            if (wk[3] < b) b = wk[3];
            sjn = (int)(unsigned)(b & 0xffffffffu);
        }
        __syncthreads();
        const int jn = sjn;
        const int jo = idxf[m];
        if (jn != jo) {
            float delta = 0.f;
            if (t < 32) {
                float4 qn = *(const float4*)(CT + (size_t)jn * EMBED + t * 4);
                float4 qo = *(const float4*)(CT + (size_t)jo * EMBED + t * 4);
                float x0 = xs[t * 4 + 0], x1 = xs[t * 4 + 1];
                float x2 = xs[t * 4 + 2], x3 = xs[t * 4 + 3];
                *(float4*)(out + (size_t)m * EMBED + t * 4) = qn;
                float dn = (qn.x - x0) * (qn.x - x0) + (qn.y - x1) * (qn.y - x1)
                         + (qn.z - x2) * (qn.z - x2) + (qn.w - x3) * (qn.w - x3);
                float dp = (qo.x - x0) * (qo.x - x0) + (qo.y - x1) * (qo.y - x1)
                         + (qo.z - x2) * (qo.z - x2) + (qo.w - x3) * (qo.w - x3);
                delta = dn - dp;
            }
            if (wave == 0) {
#pragma unroll
                for (int off = 1; off < 32; off <<= 1) delta += __shfl_xor(delta, off, 32);
                if (t == 0)
                    atomicAdd(out + OUT_ELEMS, delta * (1.25f / (float)OUT_ELEMS));
            }
        }
    }
}

extern "C" void kernel_launch(void* const* d_in, const int* in_sizes, int n_in,
                              void* d_out, int out_size, void* d_ws, size_t ws_size,
                              hipStream_t stream) {
    const float* X = (const float*)d_in[0];   // (16384,128) fp32
    const float* C = (const float*)d_in[1];   // (128,10000) fp32
    float* out = (float*)d_out;
    char* ws = (char*)d_ws;

    ushort_t* Ah = (ushort_t*)(ws + OFF_AH);
    ushort_t* Al = (ushort_t*)(ws + OFF_AL);
    float* CT    = (float*)(ws + OFF_CT);
    float* cnorm = (float*)(ws + OFF_CN);
    unsigned long long* candKey = (unsigned long long*)(ws + OFF_KEY);
    unsigned* cand2 = (unsigned*)(ws + OFF_C2);
    int* idxf    = (int*)(ws + OFF_IDX);
    int* rlist   = (int*)(ws + OFF_RL);
    int* counter = (int*)(ws + OFF_CNT);

    prep_norm<<<NCODE_PAD / 256, 256, 0, stream>>>(C, cnorm, out, counter);
    prep_c2<<<(NCODE_PAD * 18) / 256, 256, 0, stream>>>(C, cnorm, Ah, Al, CT);
    vq3<<<dim3(NSAMP / 256, NSPLIT), 256, 0, stream>>>(X, Ah, Al, candKey, cand2);
    outfin_k<<<NSAMP / 8, 256, 0, stream>>>(X, CT, candKey, cand2, idxf, rlist, counter, out);
    rescue2<<<256, 256, 0, stream>>>(X, CT, cnorm, rlist, counter, idxf, out);
}

// Round 6
// 370.456 us; speedup vs baseline: 2.4686x; 1.1095x over previous
//
#include <hip/hip_runtime.h>

#define EMBED 128
#define NCODE 10000
#define NSAMP 16384
#define NCODE_PAD 10240
#define NSPLIT 8
#define SPLIT_CODES 1280
#define NCHUNK 20                 // chunks per split, 64 codes each
#define CHUNK_ELEMS 9216          // ushorts per chunk per (h|l): 2mb*18kg*256
#define OUT_ELEMS (NSAMP * EMBED)
#define TAU 0.008f                // rescue gap threshold (> split-bf16 err bound)
#define NRS 8                     // rescue code-splits (1250 codes each)

typedef float f32x16 __attribute__((ext_vector_type(16)));
typedef short s16x8 __attribute__((ext_vector_type(8)));
typedef unsigned short ushort_t;
typedef unsigned long long u64;

// ---- ws byte offsets (~13.0 MB) ----
#define OFF_AH  0                 // Ah: 10240*144 bf16 swizzled (2.95 MB)
#define OFF_AL  2949120
#define OFF_CT  5898240           // CT fp32 [n][k] (5.24 MB)
#define OFF_CN  11141120          // cnorm fp32 [10240]
#define OFF_KEY 11182080          // candKey u64 [16384][8]
#define OFF_C2  12230656          // cand2 u32 [16384][8]
#define OFF_IDX 12754944
#define OFF_RL  12820480          // rescue list (16384 ints)
#define OFF_CNT 12886016
#define OFF_BEST 12886080         // wsBest u64 [16384]

__device__ __forceinline__ unsigned short f2bf(float f) {   // RNE fp32->bf16
    unsigned u = __float_as_uint(f);
    return (unsigned short)((u + 0x7fffu + ((u >> 16) & 1u)) >> 16);
}
__device__ __forceinline__ float bf2f(unsigned short h) {
    return __uint_as_float(((unsigned)h) << 16);
}
__device__ __forceinline__ unsigned ordf(float f) {         // order-preserving fp32->u32
    unsigned u = __float_as_uint(f);
    return (u & 0x80000000u) ? ~u : (u | 0x80000000u);
}
__device__ __forceinline__ float unordf(unsigned o) {
    return __uint_as_float((o & 0x80000000u) ? (o ^ 0x80000000u) : ~o);
}

// ---- prep: cnorm (exact fp32) + zero loss/counter ----
__global__ __launch_bounds__(256) void prep_norm(const float* __restrict__ C,
                                                 float* __restrict__ cnorm,
                                                 float* __restrict__ out,
                                                 int* __restrict__ counter) {
    int j = blockIdx.x * 256 + threadIdx.x;
    if (j == 0) { out[OUT_ELEMS] = 0.f; *counter = 0; }
    if (j >= NCODE_PAD) return;
    if (j >= NCODE) { cnorm[j] = 3.0e38f; return; }
    float s = 0.f;
#pragma unroll 8
    for (int d = 0; d < EMBED; ++d) {
        float v = C[d * NCODE + j];
        s = fmaf(v, v, s);
    }
    cnorm[j] = s;
}

// ---- prep: codes -> A-stream (swizzled, K'=144 with cn in slot 128) + CT ----
// layout: [split][chunk][mb][kg(=ks*2+kh)][row32][8]
__global__ __launch_bounds__(256) void prep_c2(const float* __restrict__ C,
                                               const float* __restrict__ cnorm,
                                               ushort_t* __restrict__ Ah,
                                               ushort_t* __restrict__ Al,
                                               float* __restrict__ CT) {
    int o = blockIdx.x * 256 + threadIdx.x;   // 184320 threads
    int n  = o % NCODE_PAD;
    int kg = o / NCODE_PAD;                   // 0..17
    int split = n / SPLIT_CODES;
    int rem   = n % SPLIT_CODES;
    int chunk = rem >> 6;
    int mb    = (rem >> 5) & 1;
    int row   = rem & 31;
    size_t eoff = ((size_t)((split * NCHUNK + chunk) * 2 + mb) * 18 + kg) * 256 + row * 8;

    float f[8];
    if (kg < 16) {
        int k0 = kg * 8;
#pragma unroll
        for (int j = 0; j < 8; ++j)
            f[j] = (n < NCODE) ? C[(size_t)(k0 + j) * NCODE + n] : 0.f;
        *(float4*)(CT + (size_t)n * EMBED + k0)     = make_float4(f[0], f[1], f[2], f[3]);
        *(float4*)(CT + (size_t)n * EMBED + k0 + 4) = make_float4(f[4], f[5], f[6], f[7]);
    } else if (kg == 16) {
        f[0] = cnorm[n];
#pragma unroll
        for (int j = 1; j < 8; ++j) f[j] = 0.f;
    } else {
#pragma unroll
        for (int j = 0; j < 8; ++j) f[j] = 0.f;
    }
    s16x8 vh, vl;
#pragma unroll
    for (int j = 0; j < 8; ++j) {
        unsigned short h = f2bf(f[j]);
        vh[j] = (short)h;
        vl[j] = (short)f2bf(f[j] - bf2f(h));
    }
    *(s16x8*)(Ah + eoff) = vh;
    *(s16x8*)(Al + eoff) = vl;
}

// ---- main: persistent-X (B), codes (A) streamed DIRECTLY from global ----
// No LDS, no barriers. dist = [c,||c||^2].[-2x,1] via 3 split-bf16 products.
__global__ __launch_bounds__(256, 2) void vq3b(const float* __restrict__ X,
                                               const ushort_t* __restrict__ Ah,
                                               const ushort_t* __restrict__ Al,
                                               unsigned long long* __restrict__ candKey,
                                               unsigned* __restrict__ cand2) {
    const int t    = threadIdx.x;
    const int lane = t & 63;
    const int wave = t >> 6;
    const int ln   = lane & 31;
    const int kh   = lane >> 5;
    const int split = blockIdx.y;
    const int m0    = blockIdx.x * 256;

    // ---- persistent B frags: samples, split(-2x) + the "1" slot at k'=128 ----
    s16x8 bh[2][9], bl[2][8];
#pragma unroll
    for (int g = 0; g < 2; ++g) {
        int m = m0 + wave * 64 + g * 32 + ln;
#pragma unroll
        for (int ks = 0; ks < 8; ++ks) {
            const float* src = X + (size_t)m * EMBED + ks * 16 + kh * 8;
            float4 f0 = *(const float4*)src;
            float4 f1 = *(const float4*)(src + 4);
            float f[8] = {f0.x, f0.y, f0.z, f0.w, f1.x, f1.y, f1.z, f1.w};
            s16x8 vh, vl;
#pragma unroll
            for (int j = 0; j < 8; ++j) {
                float v = -2.f * f[j];
                unsigned short h = f2bf(v);
                vh[j] = (short)h;
                vl[j] = (short)f2bf(v - bf2f(h));
            }
            bh[g][ks] = vh;
            bl[g][ks] = vl;
        }
        s16x8 one = {0, 0, 0, 0, 0, 0, 0, 0};
        if (kh == 0) one[0] = (short)0x3F80;   // bf16 1.0 at k'=128
        bh[g][8] = one;
        // bl[g][8] is identically zero -> its 2 MFMAs are dropped below
    }

    float v1[2] = {3.4e38f, 3.4e38f}, v2[2] = {3.4e38f, 3.4e38f};
    int   j1[2] = {0, 0};

    const ushort_t* Abh = Ah + (size_t)(split * NCHUNK) * CHUNK_ELEMS;
    const ushort_t* Abl = Al + (size_t)(split * NCHUNK) * CHUNK_ELEMS;

    for (int c = 0; c < NCHUNK; ++c) {
        const size_t cb = (size_t)c * CHUNK_ELEMS;
        const int cbase = split * SPLIT_CODES + c * 64 + 4 * kh;
#pragma unroll
        for (int mb = 0; mb < 2; ++mb) {
            f32x16 acc0 = {0,0,0,0,0,0,0,0,0,0,0,0,0,0,0,0};
            f32x16 acc1 = {0,0,0,0,0,0,0,0,0,0,0,0,0,0,0,0};
#pragma unroll
            for (int ks = 0; ks < 9; ++ks) {
                const size_t fo = cb + (size_t)((mb * 18 + ks * 2 + kh) * 256 + ln * 8);
                s16x8 a_h = *(const s16x8*)(Abh + fo);
                s16x8 a_l = *(const s16x8*)(Abl + fo);
                acc0 = __builtin_amdgcn_mfma_f32_32x32x16_bf16(a_h, bh[0][ks], acc0, 0, 0, 0);
                acc1 = __builtin_amdgcn_mfma_f32_32x32x16_bf16(a_h, bh[1][ks], acc1, 0, 0, 0);
                if (ks < 8) {
                    acc0 = __builtin_amdgcn_mfma_f32_32x32x16_bf16(a_h, bl[0][ks], acc0, 0, 0, 0);
                    acc1 = __builtin_amdgcn_mfma_f32_32x32x16_bf16(a_h, bl[1][ks], acc1, 0, 0, 0);
                }
                acc0 = __builtin_amdgcn_mfma_f32_32x32x16_bf16(a_l, bh[0][ks], acc0, 0, 0, 0);
                acc1 = __builtin_amdgcn_mfma_f32_32x32x16_bf16(a_l, bh[1][ks], acc1, 0, 0, 0);
            }
            // per-lane top-2 over the 16 code-rows this lane holds (no shuffles)
#pragma unroll
            for (int r = 0; r < 16; ++r) {
                int code = cbase + mb * 32 + ((r & 3) + 8 * (r >> 2));
                float d0 = acc0[r];
                if (d0 < v1[0]) { v2[0] = v1[0]; v1[0] = d0; j1[0] = code; }
                else            { v2[0] = fminf(v2[0], d0); }
                float d1 = acc1[r];
                if (d1 < v1[1]) { v2[1] = v1[1]; v1[1] = d1; j1[1] = code; }
                else            { v2[1] = fminf(v2[1], d1); }
            }
        }
    }

    // merge lane^32 (same sample, other code-half), emit per-split top-2
#pragma unroll
    for (int g = 0; g < 2; ++g) {
        float ov1 = __shfl_xor(v1[g], 32, 64);
        int   oj1 = __shfl_xor(j1[g], 32, 64);
        float ov2 = __shfl_xor(v2[g], 32, 64);
        float hi = fmaxf(v1[g], ov1);
        v2[g] = fminf(fminf(v2[g], ov2), hi);
        if (ov1 < v1[g] || (ov1 == v1[g] && oj1 < j1[g])) { v1[g] = ov1; j1[g] = oj1; }
        if (kh == 0) {
            int m = m0 + wave * 64 + g * 32 + ln;
            candKey[(size_t)m * NSPLIT + split] =
                ((unsigned long long)ordf(v1[g]) << 32) | (unsigned)j1[g];
            cand2[(size_t)m * NSPLIT + split] = ordf(v2[g]);
        }
    }
}

// ---- fused finalize + output: merge 8 candidates, flag near-ties, gather, loss ----
__global__ __launch_bounds__(256) void outfin_k(const float* __restrict__ X,
                                                const float* __restrict__ CT,
                                                const unsigned long long* __restrict__ candKey,
                                                const unsigned* __restrict__ cand2,
                                                int* __restrict__ idxf,
                                                int* __restrict__ rlist,
                                                int* __restrict__ counter,
                                                u64* __restrict__ wsBest,
                                                float* __restrict__ out) {
    __shared__ float red[4];
    const int t = threadIdx.x;
    const int m = blockIdx.x * 8 + (t >> 5);
    const int l = t & 31;

    int code = 0;
    if (l == 0) {
        unsigned long long best = 0xffffffffffffffffull;
        float v2 = 3.4e38f;
#pragma unroll
        for (int s = 0; s < NSPLIT; ++s) {
            unsigned long long k = candKey[(size_t)m * NSPLIT + s];
            unsigned o2 = cand2[(size_t)m * NSPLIT + s];
            if (k < best) {
                if (best != 0xffffffffffffffffull)
                    v2 = fminf(v2, unordf((unsigned)(best >> 32)));
                best = k;
                v2 = fminf(v2, unordf(o2));
            } else {
                v2 = fminf(v2, unordf((unsigned)(k >> 32)));
            }
        }
        code = (int)(unsigned)(best & 0xffffffffu);
        idxf[m] = code;
        float v1 = unordf((unsigned)(best >> 32));
        if (v2 - v1 <= TAU) {
            rlist[atomicAdd(counter, 1)] = m;
            wsBest[m] = 0xffffffffffffffffull;   // init for rescue atomicMin
        }
    }
    code = __shfl(code, 0, 32);

    float4 q = *(const float4*)(CT + (size_t)code * EMBED + l * 4);
    float4 x = *(const float4*)(X + (size_t)m * EMBED + l * 4);
    *(float4*)(out + (size_t)m * EMBED + l * 4) = q;
    float dx = q.x - x.x, dy = q.y - x.y, dz = q.z - x.z, dw = q.w - x.w;
    float lsum = dx * dx + dy * dy + dz * dz + dw * dw;
#pragma unroll
    for (int off = 1; off < 64; off <<= 1) lsum += __shfl_xor(lsum, off, 64);
    if ((t & 63) == 0) red[t >> 6] = lsum;
    __syncthreads();
    if (t == 0)
        atomicAdd(out + OUT_ELEMS,
                  (red[0] + red[1] + red[2] + red[3]) * (1.25f / (float)OUT_ELEMS));
}

// ---- rescue: exact fp32 argmin, work unit = (flagged sample, code octant) ----
// Half-wave per CT row (coalesced 512 B), shuffle-reduce, atomicMin(u64) global.
__global__ __launch_bounds__(256) void rescue3(const float* __restrict__ X,
                                               const float* __restrict__ CT,
                                               const float* __restrict__ cnorm,
                                               const int* __restrict__ rlist,
                                               const int* __restrict__ counter,
                                               u64* __restrict__ wsBest) {
    __shared__ float xs[EMBED];
    __shared__ u64 wkk[4];
    const int t = threadIdx.x;
    const int lane = t & 63;
    const int wave = t >> 6;
    const int hw = t & 31;       // lane within half-wave
    const int rowoff = t >> 5;   // 0..7: row slot within block iteration
    const int cnt = *counter;
    const int nw = cnt * NRS;

    for (int w = blockIdx.x; w < nw; w += gridDim.x) {
        const int s = w >> 3, p = w & 7;
        const int m = rlist[s];
        __syncthreads();   // previous iteration's xs/wkk reads complete
        if (t < 32) {
            float4 v = *(const float4*)(X + (size_t)m * EMBED + t * 4);
            xs[t * 4 + 0] = v.x; xs[t * 4 + 1] = v.y;
            xs[t * 4 + 2] = v.z; xs[t * 4 + 3] = v.w;
        }
        __syncthreads();
        const float x0 = xs[hw * 4 + 0], x1 = xs[hw * 4 + 1];
        const float x2 = xs[hw * 4 + 2], x3 = xs[hw * 4 + 3];
        const int base = p * 1250;
        const int jend = min(base + 1250, NCODE);
        u64 bk = 0xffffffffffffffffull;
        for (int it = 0; it < 157; ++it) {
            int row = base + it * 8 + rowoff;
            bool ok = (row < jend);
            float4 cv = ok ? *(const float4*)(CT + (size_t)row * EMBED + hw * 4)
                           : make_float4(0.f, 0.f, 0.f, 0.f);
            float part = x0 * cv.x;
            part = fmaf(x1, cv.y, part);
            part = fmaf(x2, cv.z, part);
            part = fmaf(x3, cv.w, part);
#pragma unroll
            for (int off = 1; off < 32; off <<= 1)
                part += __shfl_xor(part, off, 32);
            if (ok && hw == 0) {
                float d = fmaf(-2.f, part, cnorm[row]);
                u64 key = ((u64)ordf(d) << 32) | (unsigned)row;
                if (key < bk) bk = key;
            }
        }
#pragma unroll
        for (int off = 1; off < 64; off <<= 1) {
            u64 o = __shfl_xor(bk, off, 64);
            if (o < bk) bk = o;
        }
        if (lane == 0) wkk[wave] = bk;
        __syncthreads();
        if (t == 0) {
            u64 b = wkk[0];
            if (wkk[1] < b) b = wkk[1];
            if (wkk[2] < b) b = wkk[2];
            if (wkk[3] < b) b = wkk[3];
            atomicMin(&wsBest[m], b);
        }
    }
}

// ---- patch: apply argmin flips found by rescue ----
__global__ __launch_bounds__(256) void patch_k(const float* __restrict__ X,
                                               const float* __restrict__ CT,
                                               const int* __restrict__ rlist,
                                               const int* __restrict__ counter,
                                               const u64* __restrict__ wsBest,
                                               const int* __restrict__ idxf,
                                               float* __restrict__ out) {
    const int t = threadIdx.x;
    const int l = t & 31, sl = t >> 5;
    const int cnt = *counter;
    for (int s = blockIdx.x * 8 + sl; s < cnt; s += gridDim.x * 8) {
        int m = rlist[s];
        u64 key = wsBest[m];
        int jn = (int)(unsigned)(key & 0xffffffffu);
        int jo = idxf[m];
        if (jn == jo) continue;   // uniform within 32-lane group
        float4 qn = *(const float4*)(CT + (size_t)jn * EMBED + l * 4);
        float4 qo = *(const float4*)(CT + (size_t)jo * EMBED + l * 4);
        float4 x  = *(const float4*)(X + (size_t)m * EMBED + l * 4);
        *(float4*)(out + (size_t)m * EMBED + l * 4) = qn;
        float dn = (qn.x - x.x) * (qn.x - x.x) + (qn.y - x.y) * (qn.y - x.y)
                 + (qn.z - x.z) * (qn.z - x.z) + (qn.w - x.w) * (qn.w - x.w);
        float dp = (qo.x - x.x) * (qo.x - x.x) + (qo.y - x.y) * (qo.y - x.y)
                 + (qo.z - x.z) * (qo.z - x.z) + (qo.w - x.w) * (qo.w - x.w);
        float delta = dn - dp;
#pragma unroll
        for (int off = 1; off < 32; off <<= 1) delta += __shfl_xor(delta, off, 32);
        if (l == 0)
            atomicAdd(out + OUT_ELEMS, delta * (1.25f / (float)OUT_ELEMS));
    }
}

extern "C" void kernel_launch(void* const* d_in, const int* in_sizes, int n_in,
                              void* d_out, int out_size, void* d_ws, size_t ws_size,
                              hipStream_t stream) {
    const float* X = (const float*)d_in[0];   // (16384,128) fp32
    const float* C = (const float*)d_in[1];   // (128,10000) fp32
    float* out = (float*)d_out;
    char* ws = (char*)d_ws;

    ushort_t* Ah = (ushort_t*)(ws + OFF_AH);
    ushort_t* Al = (ushort_t*)(ws + OFF_AL);
    float* CT    = (float*)(ws + OFF_CT);
    float* cnorm = (float*)(ws + OFF_CN);
    unsigned long long* candKey = (unsigned long long*)(ws + OFF_KEY);
    unsigned* cand2 = (unsigned*)(ws + OFF_C2);
    int* idxf    = (int*)(ws + OFF_IDX);
    int* rlist   = (int*)(ws + OFF_RL);
    int* counter = (int*)(ws + OFF_CNT);
    u64* wsBest  = (u64*)(ws + OFF_BEST);

    prep_norm<<<NCODE_PAD / 256, 256, 0, stream>>>(C, cnorm, out, counter);
    prep_c2<<<(NCODE_PAD * 18) / 256, 256, 0, stream>>>(C, cnorm, Ah, Al, CT);
    vq3b<<<dim3(NSAMP / 256, NSPLIT), 256, 0, stream>>>(X, Ah, Al, candKey, cand2);
    outfin_k<<<NSAMP / 8, 256, 0, stream>>>(X, CT, candKey, cand2, idxf, rlist, counter, wsBest, out);
    rescue3<<<512, 256, 0, stream>>>(X, CT, cnorm, rlist, counter, wsBest);
    patch_k<<<64, 256, 0, stream>>>(X, CT, rlist, counter, wsBest, idxf, out);
}

// Round 7
// 324.673 us; speedup vs baseline: 2.8167x; 1.1410x over previous
//
#include <hip/hip_runtime.h>

#define EMBED 128
#define NCODE 10000
#define NSAMP 16384
#define NCODE_PAD 10240
#define NSPLIT 8
#define SPLIT_CODES 1280
#define NCHUNK 20                 // chunks per split, 64 codes each
#define CHUNK_ELEMS 9216          // ushorts per chunk per (h|l): 2mb*18kg*256
#define OUT_ELEMS (NSAMP * EMBED)
#define TAU 0.008f                // rescue gap threshold (> split-bf16 err bound)
#define NRS 8                     // rescue code-splits (1250 codes each)

typedef float f32x16 __attribute__((ext_vector_type(16)));
typedef short s16x8 __attribute__((ext_vector_type(8)));
typedef unsigned short ushort_t;
typedef unsigned long long u64;

// ---- ws byte offsets (~13.0 MB) ----
#define OFF_AH  0                 // Ah: 10240*144 bf16 swizzled (2.95 MB)
#define OFF_AL  2949120
#define OFF_CT  5898240           // CT fp32 [n][k] (5.24 MB)
#define OFF_CN  11141120          // cnorm fp32 [10240]
#define OFF_KEY 11182080          // candKey u64 [16384][8]
#define OFF_C2  12230656          // cand2 u32 [16384][8]
#define OFF_IDX 12754944
#define OFF_RL  12820480          // rescue list (16384 ints)
#define OFF_CNT 12886016
#define OFF_BEST 12886080         // wsBest u64 [16384]

__device__ __forceinline__ unsigned short f2bf(float f) {   // RNE fp32->bf16
    unsigned u = __float_as_uint(f);
    return (unsigned short)((u + 0x7fffu + ((u >> 16) & 1u)) >> 16);
}
__device__ __forceinline__ float bf2f(unsigned short h) {
    return __uint_as_float(((unsigned)h) << 16);
}
__device__ __forceinline__ unsigned ordf(float f) {         // order-preserving fp32->u32
    unsigned u = __float_as_uint(f);
    return (u & 0x80000000u) ? ~u : (u | 0x80000000u);
}
__device__ __forceinline__ float unordf(unsigned o) {
    return __uint_as_float((o & 0x80000000u) ? (o ^ 0x80000000u) : ~o);
}

// ---- prep: cnorm (exact fp32) + zero loss/counter ----
__global__ __launch_bounds__(256) void prep_norm(const float* __restrict__ C,
                                                 float* __restrict__ cnorm,
                                                 float* __restrict__ out,
                                                 int* __restrict__ counter) {
    int j = blockIdx.x * 256 + threadIdx.x;
    if (j == 0) { out[OUT_ELEMS] = 0.f; *counter = 0; }
    if (j >= NCODE_PAD) return;
    if (j >= NCODE) { cnorm[j] = 3.0e38f; return; }
    float s = 0.f;
#pragma unroll 8
    for (int d = 0; d < EMBED; ++d) {
        float v = C[d * NCODE + j];
        s = fmaf(v, v, s);
    }
    cnorm[j] = s;
}

// ---- prep: codes -> A-stream (swizzled, K'=144 with cn in slot 128) + CT ----
// layout: [split][chunk][mb][kg(=ks*2+kh)][row32][8]
__global__ __launch_bounds__(256) void prep_c2(const float* __restrict__ C,
                                               const float* __restrict__ cnorm,
                                               ushort_t* __restrict__ Ah,
                                               ushort_t* __restrict__ Al,
                                               float* __restrict__ CT) {
    int o = blockIdx.x * 256 + threadIdx.x;   // 184320 threads
    int n  = o % NCODE_PAD;
    int kg = o / NCODE_PAD;                   // 0..17
    int split = n / SPLIT_CODES;
    int rem   = n % SPLIT_CODES;
    int chunk = rem >> 6;
    int mb    = (rem >> 5) & 1;
    int row   = rem & 31;
    size_t eoff = ((size_t)((split * NCHUNK + chunk) * 2 + mb) * 18 + kg) * 256 + row * 8;

    float f[8];
    if (kg < 16) {
        int k0 = kg * 8;
#pragma unroll
        for (int j = 0; j < 8; ++j)
            f[j] = (n < NCODE) ? C[(size_t)(k0 + j) * NCODE + n] : 0.f;
        *(float4*)(CT + (size_t)n * EMBED + k0)     = make_float4(f[0], f[1], f[2], f[3]);
        *(float4*)(CT + (size_t)n * EMBED + k0 + 4) = make_float4(f[4], f[5], f[6], f[7]);
    } else if (kg == 16) {
        f[0] = cnorm[n];
#pragma unroll
        for (int j = 1; j < 8; ++j) f[j] = 0.f;
    } else {
#pragma unroll
        for (int j = 0; j < 8; ++j) f[j] = 0.f;
    }
    s16x8 vh, vl;
#pragma unroll
    for (int j = 0; j < 8; ++j) {
        unsigned short h = f2bf(f[j]);
        vh[j] = (short)h;
        vl[j] = (short)f2bf(f[j] - bf2f(h));
    }
    *(s16x8*)(Ah + eoff) = vh;
    *(s16x8*)(Al + eoff) = vl;
}

// ---- main: persistent-X (B), codes (A) via double-buffered LDS pipeline ----
// dist = [c,||c||^2].[-2x,1] via 3 split-bf16 products; argmin per-lane.
// Pipeline: prefetch chunk c+1 (global_load_lds) -> compute chunk c -> barrier.
__global__ __launch_bounds__(256, 2) void vq4(const float* __restrict__ X,
                                              const ushort_t* __restrict__ Ah,
                                              const ushort_t* __restrict__ Al,
                                              unsigned long long* __restrict__ candKey,
                                              unsigned* __restrict__ cand2) {
    __shared__ ushort_t Bs[2 * 2 * CHUNK_ELEMS];   // 72 KB: buf{0,1} x {h,l}
    const int t    = threadIdx.x;
    const int lane = t & 63;
    const int wave = t >> 6;
    const int ln   = lane & 31;
    const int kh   = lane >> 5;
    const int split = blockIdx.y;
    const int m0    = blockIdx.x * 256;

    // ---- persistent B frags: samples, split(-2x) + the "1" slot at k'=128 ----
    s16x8 bh[2][9], bl[2][8];
#pragma unroll
    for (int g = 0; g < 2; ++g) {
        int m = m0 + wave * 64 + g * 32 + ln;
#pragma unroll
        for (int ks = 0; ks < 8; ++ks) {
            const float* src = X + (size_t)m * EMBED + ks * 16 + kh * 8;
            float4 f0 = *(const float4*)src;
            float4 f1 = *(const float4*)(src + 4);
            float f[8] = {f0.x, f0.y, f0.z, f0.w, f1.x, f1.y, f1.z, f1.w};
            s16x8 vh, vl;
#pragma unroll
            for (int j = 0; j < 8; ++j) {
                float v = -2.f * f[j];
                unsigned short h = f2bf(v);
                vh[j] = (short)h;
                vl[j] = (short)f2bf(v - bf2f(h));
            }
            bh[g][ks] = vh;
            bl[g][ks] = vl;
        }
        s16x8 one = {0, 0, 0, 0, 0, 0, 0, 0};
        if (kh == 0) one[0] = (short)0x3F80;   // bf16 1.0 at k'=128
        bh[g][8] = one;
        // bl[g][8] is identically zero -> its MFMAs are dropped below
    }

    float v1[2] = {3.4e38f, 3.4e38f}, v2[2] = {3.4e38f, 3.4e38f};
    int   j1[2] = {0, 0};

    auto ldsw = (__attribute__((address_space(3))) ushort_t*)Bs;
    // wave role: waves 0,1 stage the h-half; waves 2,3 stage the l-half
    const ushort_t* srcA = (wave < 2) ? Ah : Al;
    const int wdst = (wave >> 1) * CHUNK_ELEMS + (wave & 1) * 4608;
    const size_t chbase = (size_t)(split * NCHUNK) * CHUNK_ELEMS;

    // ---- stage chunk 0 into buf 0 ----
    {
        const ushort_t* s = srcA + chbase + (wave & 1) * 4608 + lane * 8;
#pragma unroll
        for (int i = 0; i < 9; ++i)
            __builtin_amdgcn_global_load_lds(
                (const __attribute__((address_space(1))) void*)(s + i * 512),
                (__attribute__((address_space(3))) void*)(ldsw + wdst + i * 512),
                16, 0, 0);
    }
    __syncthreads();

    for (int c = 0; c < NCHUNK; ++c) {
        const int b = c & 1;
        // ---- prefetch chunk c+1 into the other buffer (async, no wait) ----
        if (c + 1 < NCHUNK) {
            const ushort_t* s = srcA + chbase + (size_t)(c + 1) * CHUNK_ELEMS
                                + (wave & 1) * 4608 + lane * 8;
            const int db = (1 - b) * 2 * CHUNK_ELEMS + wdst;
#pragma unroll
            for (int i = 0; i < 9; ++i)
                __builtin_amdgcn_global_load_lds(
                    (const __attribute__((address_space(1))) void*)(s + i * 512),
                    (__attribute__((address_space(3))) void*)(ldsw + db + i * 512),
                    16, 0, 0);
        }

        // ---- compute chunk c from buf b: 4 live acc chains (mb x g) ----
        const int bb = b * 2 * CHUNK_ELEMS;
        f32x16 acc00 = {0,0,0,0,0,0,0,0,0,0,0,0,0,0,0,0};
        f32x16 acc01 = {0,0,0,0,0,0,0,0,0,0,0,0,0,0,0,0};
        f32x16 acc10 = {0,0,0,0,0,0,0,0,0,0,0,0,0,0,0,0};
        f32x16 acc11 = {0,0,0,0,0,0,0,0,0,0,0,0,0,0,0,0};
#pragma unroll
        for (int ks = 0; ks < 9; ++ks) {
            const int fo0 = bb + (ks * 2 + kh) * 256 + ln * 8;            // mb=0
            const int fo1 = bb + ((18 + ks * 2 + kh)) * 256 + ln * 8;     // mb=1
            s16x8 a_h0 = *(const s16x8*)&Bs[fo0];
            s16x8 a_h1 = *(const s16x8*)&Bs[fo1];
            s16x8 a_l0 = *(const s16x8*)&Bs[CHUNK_ELEMS + fo0];
            s16x8 a_l1 = *(const s16x8*)&Bs[CHUNK_ELEMS + fo1];
            acc00 = __builtin_amdgcn_mfma_f32_32x32x16_bf16(a_h0, bh[0][ks], acc00, 0, 0, 0);
            acc01 = __builtin_amdgcn_mfma_f32_32x32x16_bf16(a_h0, bh[1][ks], acc01, 0, 0, 0);
            acc10 = __builtin_amdgcn_mfma_f32_32x32x16_bf16(a_h1, bh[0][ks], acc10, 0, 0, 0);
            acc11 = __builtin_amdgcn_mfma_f32_32x32x16_bf16(a_h1, bh[1][ks], acc11, 0, 0, 0);
            if (ks < 8) {
                acc00 = __builtin_amdgcn_mfma_f32_32x32x16_bf16(a_h0, bl[0][ks], acc00, 0, 0, 0);
                acc01 = __builtin_amdgcn_mfma_f32_32x32x16_bf16(a_h0, bl[1][ks], acc01, 0, 0, 0);
                acc10 = __builtin_amdgcn_mfma_f32_32x32x16_bf16(a_h1, bl[0][ks], acc10, 0, 0, 0);
                acc11 = __builtin_amdgcn_mfma_f32_32x32x16_bf16(a_h1, bl[1][ks], acc11, 0, 0, 0);
            }
            acc00 = __builtin_amdgcn_mfma_f32_32x32x16_bf16(a_l0, bh[0][ks], acc00, 0, 0, 0);
            acc01 = __builtin_amdgcn_mfma_f32_32x32x16_bf16(a_l0, bh[1][ks], acc01, 0, 0, 0);
            acc10 = __builtin_amdgcn_mfma_f32_32x32x16_bf16(a_l1, bh[0][ks], acc10, 0, 0, 0);
            acc11 = __builtin_amdgcn_mfma_f32_32x32x16_bf16(a_l1, bh[1][ks], acc11, 0, 0, 0);
        }

        // ---- per-lane top-2 update (no shuffles) ----
        const int cbase = split * SPLIT_CODES + c * 64 + 4 * kh;
#pragma unroll
        for (int r = 0; r < 16; ++r) {
            int code0 = cbase + ((r & 3) + 8 * (r >> 2));
            int code1 = code0 + 32;
            float d;
            d = acc00[r];
            if (d < v1[0]) { v2[0] = v1[0]; v1[0] = d; j1[0] = code0; }
            else           { v2[0] = fminf(v2[0], d); }
            d = acc10[r];
            if (d < v1[0]) { v2[0] = v1[0]; v1[0] = d; j1[0] = code1; }
            else           { v2[0] = fminf(v2[0], d); }
            d = acc01[r];
            if (d < v1[1]) { v2[1] = v1[1]; v1[1] = d; j1[1] = code0; }
            else           { v2[1] = fminf(v2[1], d); }
            d = acc11[r];
            if (d < v1[1]) { v2[1] = v1[1]; v1[1] = d; j1[1] = code1; }
            else           { v2[1] = fminf(v2[1], d); }
        }
        __syncthreads();   // all reads of buf b done; prefetch into 1-b drained
    }

    // merge lane^32 (same sample, other code-subset), emit per-split top-2
#pragma unroll
    for (int g = 0; g < 2; ++g) {
        float ov1 = __shfl_xor(v1[g], 32, 64);
        int   oj1 = __shfl_xor(j1[g], 32, 64);
        float ov2 = __shfl_xor(v2[g], 32, 64);
        float hi = fmaxf(v1[g], ov1);
        v2[g] = fminf(fminf(v2[g], ov2), hi);
        if (ov1 < v1[g] || (ov1 == v1[g] && oj1 < j1[g])) { v1[g] = ov1; j1[g] = oj1; }
        if (kh == 0) {
            int m = m0 + wave * 64 + g * 32 + ln;
            candKey[(size_t)m * NSPLIT + split] =
                ((unsigned long long)ordf(v1[g]) << 32) | (unsigned)j1[g];
            cand2[(size_t)m * NSPLIT + split] = ordf(v2[g]);
        }
    }
}

// ---- fused finalize + output: merge 8 candidates, flag near-ties, gather, loss ----
__global__ __launch_bounds__(256) void outfin_k(const float* __restrict__ X,
                                                const float* __restrict__ CT,
                                                const unsigned long long* __restrict__ candKey,
                                                const unsigned* __restrict__ cand2,
                                                int* __restrict__ idxf,
                                                int* __restrict__ rlist,
                                                int* __restrict__ counter,
                                                u64* __restrict__ wsBest,
                                                float* __restrict__ out) {
    __shared__ float red[4];
    const int t = threadIdx.x;
    const int m = blockIdx.x * 8 + (t >> 5);
    const int l = t & 31;

    int code = 0;
    if (l == 0) {
        unsigned long long best = 0xffffffffffffffffull;
        float v2 = 3.4e38f;
#pragma unroll
        for (int s = 0; s < NSPLIT; ++s) {
            unsigned long long k = candKey[(size_t)m * NSPLIT + s];
            unsigned o2 = cand2[(size_t)m * NSPLIT + s];
            if (k < best) {
                if (best != 0xffffffffffffffffull)
                    v2 = fminf(v2, unordf((unsigned)(best >> 32)));
                best = k;
                v2 = fminf(v2, unordf(o2));
            } else {
                v2 = fminf(v2, unordf((unsigned)(k >> 32)));
            }
        }
        code = (int)(unsigned)(best & 0xffffffffu);
        idxf[m] = code;
        float v1 = unordf((unsigned)(best >> 32));
        if (v2 - v1 <= TAU) {
            rlist[atomicAdd(counter, 1)] = m;
            wsBest[m] = 0xffffffffffffffffull;   // init for rescue atomicMin
        }
    }
    code = __shfl(code, 0, 32);

    float4 q = *(const float4*)(CT + (size_t)code * EMBED + l * 4);
    float4 x = *(const float4*)(X + (size_t)m * EMBED + l * 4);
    *(float4*)(out + (size_t)m * EMBED + l * 4) = q;
    float dx = q.x - x.x, dy = q.y - x.y, dz = q.z - x.z, dw = q.w - x.w;
    float lsum = dx * dx + dy * dy + dz * dz + dw * dw;
#pragma unroll
    for (int off = 1; off < 64; off <<= 1) lsum += __shfl_xor(lsum, off, 64);
    if ((t & 63) == 0) red[t >> 6] = lsum;
    __syncthreads();
    if (t == 0)
        atomicAdd(out + OUT_ELEMS,
                  (red[0] + red[1] + red[2] + red[3]) * (1.25f / (float)OUT_ELEMS));
}

// ---- rescue: exact fp32 argmin, work unit = (flagged sample, code octant) ----
__global__ __launch_bounds__(256) void rescue3(const float* __restrict__ X,
                                               const float* __restrict__ CT,
                                               const float* __restrict__ cnorm,
                                               const int* __restrict__ rlist,
                                               const int* __restrict__ counter,
                                               u64* __restrict__ wsBest) {
    __shared__ float xs[EMBED];
    __shared__ u64 wkk[4];
    const int t = threadIdx.x;
    const int lane = t & 63;
    const int wave = t >> 6;
    const int hw = t & 31;       // lane within half-wave
    const int rowoff = t >> 5;   // 0..7: row slot within block iteration
    const int cnt = *counter;
    const int nw = cnt * NRS;

    for (int w = blockIdx.x; w < nw; w += gridDim.x) {
        const int s = w >> 3, p = w & 7;
        const int m = rlist[s];
        __syncthreads();   // previous iteration's xs/wkk reads complete
        if (t < 32) {
            float4 v = *(const float4*)(X + (size_t)m * EMBED + t * 4);
            xs[t * 4 + 0] = v.x; xs[t * 4 + 1] = v.y;
            xs[t * 4 + 2] = v.z; xs[t * 4 + 3] = v.w;
        }
        __syncthreads();
        const float x0 = xs[hw * 4 + 0], x1 = xs[hw * 4 + 1];
        const float x2 = xs[hw * 4 + 2], x3 = xs[hw * 4 + 3];
        const int base = p * 1250;
        const int jend = min(base + 1250, NCODE);
        u64 bk = 0xffffffffffffffffull;
        for (int it = 0; it < 157; ++it) {
            int row = base + it * 8 + rowoff;
            bool ok = (row < jend);
            float4 cv = ok ? *(const float4*)(CT + (size_t)row * EMBED + hw * 4)
                           : make_float4(0.f, 0.f, 0.f, 0.f);
            float part = x0 * cv.x;
            part = fmaf(x1, cv.y, part);
            part = fmaf(x2, cv.z, part);
            part = fmaf(x3, cv.w, part);
#pragma unroll
            for (int off = 1; off < 32; off <<= 1)
                part += __shfl_xor(part, off, 32);
            if (ok && hw == 0) {
                float d = fmaf(-2.f, part, cnorm[row]);
                u64 key = ((u64)ordf(d) << 32) | (unsigned)row;
                if (key < bk) bk = key;
            }
        }
#pragma unroll
        for (int off = 1; off < 64; off <<= 1) {
            u64 o = __shfl_xor(bk, off, 64);
            if (o < bk) bk = o;
        }
        if (lane == 0) wkk[wave] = bk;
        __syncthreads();
        if (t == 0) {
            u64 b = wkk[0];
            if (wkk[1] < b) b = wkk[1];
            if (wkk[2] < b) b = wkk[2];
            if (wkk[3] < b) b = wkk[3];
            atomicMin(&wsBest[m], b);
        }
    }
}

// ---- patch: apply argmin flips found by rescue ----
__global__ __launch_bounds__(256) void patch_k(const float* __restrict__ X,
                                               const float* __restrict__ CT,
                                               const int* __restrict__ rlist,
                                               const int* __restrict__ counter,
                                               const u64* __restrict__ wsBest,
                                               const int* __restrict__ idxf,
                                               float* __restrict__ out) {
    const int t = threadIdx.x;
    const int l = t & 31, sl = t >> 5;
    const int cnt = *counter;
    for (int s = blockIdx.x * 8 + sl; s < cnt; s += gridDim.x * 8) {
        int m = rlist[s];
        u64 key = wsBest[m];
        int jn = (int)(unsigned)(key & 0xffffffffu);
        int jo = idxf[m];
        if (jn == jo) continue;   // uniform within 32-lane group
        float4 qn = *(const float4*)(CT + (size_t)jn * EMBED + l * 4);
        float4 qo = *(const float4*)(CT + (size_t)jo * EMBED + l * 4);
        float4 x  = *(const float4*)(X + (size_t)m * EMBED + l * 4);
        *(float4*)(out + (size_t)m * EMBED + l * 4) = qn;
        float dn = (qn.x - x.x) * (qn.x - x.x) + (qn.y - x.y) * (qn.y - x.y)
                 + (qn.z - x.z) * (qn.z - x.z) + (qn.w - x.w) * (qn.w - x.w);
        float dp = (qo.x - x.x) * (qo.x - x.x) + (qo.y - x.y) * (qo.y - x.y)
                 + (qo.z - x.z) * (qo.z - x.z) + (qo.w - x.w) * (qo.w - x.w);
        float delta = dn - dp;
#pragma unroll
        for (int off = 1; off < 32; off <<= 1) delta += __shfl_xor(delta, off, 32);
        if (l == 0)
            atomicAdd(out + OUT_ELEMS, delta * (1.25f / (float)OUT_ELEMS));
    }
}

extern "C" void kernel_launch(void* const* d_in, const int* in_sizes, int n_in,
                              void* d_out, int out_size, void* d_ws, size_t ws_size,
                              hipStream_t stream) {
    const float* X = (const float*)d_in[0];   // (16384,128) fp32
    const float* C = (const float*)d_in[1];   // (128,10000) fp32
    float* out = (float*)d_out;
    char* ws = (char*)d_ws;

    ushort_t* Ah = (ushort_t*)(ws + OFF_AH);
    ushort_t* Al = (ushort_t*)(ws + OFF_AL);
    float* CT    = (float*)(ws + OFF_CT);
    float* cnorm = (float*)(ws + OFF_CN);
    unsigned long long* candKey = (unsigned long long*)(ws + OFF_KEY);
    unsigned* cand2 = (unsigned*)(ws + OFF_C2);
    int* idxf    = (int*)(ws + OFF_IDX);
    int* rlist   = (int*)(ws + OFF_RL);
    int* counter = (int*)(ws + OFF_CNT);
    u64* wsBest  = (u64*)(ws + OFF_BEST);

    prep_norm<<<NCODE_PAD / 256, 256, 0, stream>>>(C, cnorm, out, counter);
    prep_c2<<<(NCODE_PAD * 18) / 256, 256, 0, stream>>>(C, cnorm, Ah, Al, CT);
    vq4<<<dim3(NSAMP / 256, NSPLIT), 256, 0, stream>>>(X, Ah, Al, candKey, cand2);
    outfin_k<<<NSAMP / 8, 256, 0, stream>>>(X, CT, candKey, cand2, idxf, rlist, counter, wsBest, out);
    rescue3<<<512, 256, 0, stream>>>(X, CT, cnorm, rlist, counter, wsBest);
    patch_k<<<64, 256, 0, stream>>>(X, CT, rlist, counter, wsBest, idxf, out);
}